// Round 1
// baseline (183.007 us; speedup 1.0000x reference)
//
#include <hip/hip_runtime.h>
#include <math.h>

#define KC 3
#define S 12
#define SS 1728          // 12^3 composite states (without chain label)
#define AB 32
#define TLEN 64
#define NTHREADS 512
#define NWAVES (NTHREADS/64)

__global__ __launch_bounds__(NTHREADS)
void hmm_fwd_kernel(const int* __restrict__ ys,
                    const float* __restrict__ transition,  // [3][12][12]
                    const float* __restrict__ emission,    // [3][12][32]
                    const float* __restrict__ choice,      // [3]
                    const float* __restrict__ prior,       // [3][12]
                    float* __restrict__ out)
{
    __shared__ float t_lin[KC][S][S];    // exp(log_softmax(transition)) = row-softmax probs
    __shared__ float e_ls[KC][S][AB];    // log_softmax(emission)
    __shared__ float c_ls[KC];
    __shared__ float p_ls[KC][S];
    __shared__ float alpha[SS * KC];     // alpha[s*3 + k]
    __shared__ float beta[SS];
    __shared__ int   ys_s[TLEN];
    __shared__ float redm[NWAVES];
    __shared__ float gmax_s;

    const int tid = threadIdx.x;

    // ---- stage inputs / precompute log-softmax tables ----
    if (tid < TLEN) ys_s[tid] = ys[tid];

    if (tid == 0) {
        float m = fmaxf(fmaxf(choice[0], choice[1]), choice[2]);
        float s = expf(choice[0]-m) + expf(choice[1]-m) + expf(choice[2]-m);
        float l = m + logf(s);
        #pragma unroll
        for (int k = 0; k < KC; ++k) c_ls[k] = choice[k] - l;
    }
    if (tid >= 1 && tid < 1 + KC) {          // prior rows
        int k = tid - 1;
        float m = -INFINITY;
        #pragma unroll
        for (int i = 0; i < S; ++i) m = fmaxf(m, prior[k*S + i]);
        float s = 0.f;
        #pragma unroll
        for (int i = 0; i < S; ++i) s += expf(prior[k*S + i] - m);
        float l = m + logf(s);
        #pragma unroll
        for (int i = 0; i < S; ++i) p_ls[k][i] = prior[k*S + i] - l;
    }
    if (tid >= 64 && tid < 64 + KC*S) {      // transition rows -> linear-space softmax
        int r = tid - 64;
        int k = r / S, i = r % S;
        const float* row = transition + (k*S + i)*S;
        float m = -INFINITY;
        #pragma unroll
        for (int j = 0; j < S; ++j) m = fmaxf(m, row[j]);
        float ev[S]; float s = 0.f;
        #pragma unroll
        for (int j = 0; j < S; ++j) { ev[j] = expf(row[j] - m); s += ev[j]; }
        float inv = 1.f / s;
        #pragma unroll
        for (int j = 0; j < S; ++j) t_lin[k][i][j] = ev[j] * inv;
    }
    if (tid >= 128 && tid < 128 + KC*S) {    // emission rows -> log_softmax
        int r = tid - 128;
        int k = r / S, si = r % S;
        const float* row = emission + (k*S + si)*AB;
        float m = -INFINITY;
        #pragma unroll
        for (int a = 0; a < AB; ++a) m = fmaxf(m, row[a]);
        float s = 0.f;
        #pragma unroll
        for (int a = 0; a < AB; ++a) s += expf(row[a] - m);
        float l = m + logf(s);
        #pragma unroll
        for (int a = 0; a < AB; ++a) e_ls[k][si][a] = row[a] - l;
    }
    __syncthreads();

    // ---- alpha0[s,k] = sum_c p_ls[c][s_c] + c_ls[k] ----
    for (int idx = tid; idx < SS; idx += NTHREADS) {
        int s0 = idx / 144, s1 = (idx / 12) % 12, s2 = idx % 12;
        float base = p_ls[0][s0] + p_ls[1][s1] + p_ls[2][s2];
        #pragma unroll
        for (int k = 0; k < KC; ++k) alpha[idx*KC + k] = base + c_ls[k];
    }
    __syncthreads();

    // ---- 64 sequential scan steps ----
    for (int t = 0; t < TLEN; ++t) {
        const int y = ys_s[t];

        // beta[s] = lse over chain label of alpha[s, :]
        for (int s = tid; s < SS; s += NTHREADS) {
            float a0 = alpha[s*KC+0], a1 = alpha[s*KC+1], a2 = alpha[s*KC+2];
            float m = fmaxf(fmaxf(a0, a1), a2);
            beta[s] = m + logf(expf(a0-m) + expf(a1-m) + expf(a2-m));
        }
        __syncthreads();

        // 432 slices: chain k, 144 fixed other-coords each; 12 outputs per slice
        if (tid < KC * 144) {
            const int k = tid / 144;
            const int q = tid % 144;
            int base, str;
            if (k == 0)      { base = q;                       str = 144; }
            else if (k == 1) { base = (q/12)*144 + (q%12);     str = 12;  }
            else             { base = q*12;                    str = 1;   }

            float b[S]; float m = -INFINITY;
            #pragma unroll
            for (int i = 0; i < S; ++i) { b[i] = beta[base + i*str]; m = fmaxf(m, b[i]); }
            float p[S];
            #pragma unroll
            for (int i = 0; i < S; ++i) p[i] = expf(b[i] - m);
            float acc[S];
            #pragma unroll
            for (int j = 0; j < S; ++j) acc[j] = 0.f;
            #pragma unroll
            for (int i = 0; i < S; ++i) {
                float pv = p[i];
                #pragma unroll
                for (int j = 0; j < S; ++j) acc[j] += pv * t_lin[k][i][j];
            }
            const float ck = c_ls[k] + m;
            #pragma unroll
            for (int j = 0; j < S; ++j) {
                alpha[(base + j*str)*KC + k] = e_ls[k][j][y] + ck + logf(acc[j]);
            }
        }
        __syncthreads();
    }

    // ---- final logsumexp over all 5184 alpha values ----
    float lm = -INFINITY;
    for (int i = tid; i < SS*KC; i += NTHREADS) lm = fmaxf(lm, alpha[i]);
    #pragma unroll
    for (int off = 32; off > 0; off >>= 1) lm = fmaxf(lm, __shfl_xor(lm, off));
    const int wave = tid >> 6;
    if ((tid & 63) == 0) redm[wave] = lm;
    __syncthreads();
    if (tid == 0) {
        float m = redm[0];
        #pragma unroll
        for (int w = 1; w < NWAVES; ++w) m = fmaxf(m, redm[w]);
        gmax_s = m;
    }
    __syncthreads();
    const float gm = gmax_s;
    float ls = 0.f;
    for (int i = tid; i < SS*KC; i += NTHREADS) ls += expf(alpha[i] - gm);
    #pragma unroll
    for (int off = 32; off > 0; off >>= 1) ls += __shfl_xor(ls, off);
    if ((tid & 63) == 0) redm[wave] = ls;
    __syncthreads();
    if (tid == 0) {
        float s = 0.f;
        #pragma unroll
        for (int w = 0; w < NWAVES; ++w) s += redm[w];
        out[0] = gm + logf(s);
    }
}

extern "C" void kernel_launch(void* const* d_in, const int* in_sizes, int n_in,
                              void* d_out, int out_size, void* d_ws, size_t ws_size,
                              hipStream_t stream) {
    const int*   ys         = (const int*)  d_in[0];
    const float* transition = (const float*)d_in[1];
    const float* emission   = (const float*)d_in[2];
    const float* choice     = (const float*)d_in[3];
    const float* prior      = (const float*)d_in[4];
    float* out = (float*)d_out;

    hipLaunchKernelGGL(hmm_fwd_kernel, dim3(1), dim3(NTHREADS), 0, stream,
                       ys, transition, emission, choice, prior, out);
}

// Round 2
// 104.988 us; speedup vs baseline: 1.7431x; 1.7431x over previous
//
#include <hip/hip_runtime.h>
#include <math.h>

#define KC 3
#define S 12
#define SS 1728          // 12^3 composite states (without chain label)
#define AB 32
#define TLEN 64
#define NTHREADS 512
#define NWAVES (NTHREADS/64)
#define NSLICE (KC*144)  // 432
#define LN2F 0.6931471805599453f

__global__ __launch_bounds__(NTHREADS)
void hmm_fwd_kernel(const int* __restrict__ ys,
                    const float* __restrict__ transition,  // [3][12][12]
                    const float* __restrict__ emission,    // [3][12][32]
                    const float* __restrict__ choice,      // [3]
                    const float* __restrict__ prior,       // [3][12]
                    float* __restrict__ out)
{
    __shared__ __align__(16) float T[KC][S][S];   // softmax probs, rows 48B (16B-mult)
    __shared__ float EC[KC][S][AB];               // C[k] * softmax(emission[k][j]) (linear)
    __shared__ float p_lin[KC][S];                // prior softmax probs
    __shared__ float c_lin[KC];                   // choice softmax probs
    __shared__ float A[SS * KC];                  // scaled linear alpha, A[s*3 + k]
    __shared__ float beta[SS];                    // sum over chain label (linear)
    __shared__ int   ys_s[TLEN];
    __shared__ float wsum[NWAVES];
    __shared__ float redm[NWAVES];

    const int tid = threadIdx.x;

    // ---------------- setup: stage inputs, build linear-space tables ----------------
    if (tid < TLEN) ys_s[tid] = ys[tid];

    if (tid == 0) {
        float m = fmaxf(fmaxf(choice[0], choice[1]), choice[2]);
        float e0 = __expf(choice[0]-m), e1 = __expf(choice[1]-m), e2 = __expf(choice[2]-m);
        float inv = 1.f / (e0+e1+e2);
        c_lin[0] = e0*inv; c_lin[1] = e1*inv; c_lin[2] = e2*inv;
    }
    if (tid >= 1 && tid < 1 + KC) {          // prior rows -> softmax probs
        int k = tid - 1;
        float m = -INFINITY;
        #pragma unroll
        for (int i = 0; i < S; ++i) m = fmaxf(m, prior[k*S + i]);
        float ev[S]; float s = 0.f;
        #pragma unroll
        for (int i = 0; i < S; ++i) { ev[i] = __expf(prior[k*S + i] - m); s += ev[i]; }
        float inv = 1.f / s;
        #pragma unroll
        for (int i = 0; i < S; ++i) p_lin[k][i] = ev[i] * inv;
    }
    if (tid >= 64 && tid < 64 + KC*S) {      // transition rows -> softmax probs
        int r = tid - 64;
        int k = r / S, i = r % S;
        const float* row = transition + (k*S + i)*S;
        float m = -INFINITY;
        #pragma unroll
        for (int j = 0; j < S; ++j) m = fmaxf(m, row[j]);
        float ev[S]; float s = 0.f;
        #pragma unroll
        for (int j = 0; j < S; ++j) { ev[j] = __expf(row[j] - m); s += ev[j]; }
        float inv = 1.f / s;
        #pragma unroll
        for (int j = 0; j < S; ++j) T[k][i][j] = ev[j] * inv;
    }
    if (tid >= 128 && tid < 128 + KC*S) {    // emission rows -> C[k]*softmax probs
        int r = tid - 128;
        int k = r / S, si = r % S;
        // redundant per-thread choice softmax (avoids ordering dep on c_lin)
        float cm = fmaxf(fmaxf(choice[0], choice[1]), choice[2]);
        float ce = __expf(choice[k]-cm) /
                   (__expf(choice[0]-cm) + __expf(choice[1]-cm) + __expf(choice[2]-cm));
        const float* row = emission + (k*S + si)*AB;
        float m = -INFINITY;
        #pragma unroll
        for (int a = 0; a < AB; ++a) m = fmaxf(m, row[a]);
        float ev[AB]; float s = 0.f;
        #pragma unroll
        for (int a = 0; a < AB; ++a) { ev[a] = __expf(row[a] - m); s += ev[a]; }
        float inv = ce / s;
        #pragma unroll
        for (int a = 0; a < AB; ++a) EC[k][si][a] = ev[a] * inv;
    }
    __syncthreads();

    // ---------------- init: A0[s,k] = P0[0][s0]*P0[1][s1]*P0[2][s2]*C[k] ----------------
    for (int idx = tid; idx < SS; idx += NTHREADS) {
        int s0 = idx / 144, s1 = (idx / 12) % 12, s2 = idx % 12;
        float pr = p_lin[0][s0] * p_lin[1][s1] * p_lin[2][s2];
        #pragma unroll
        for (int k = 0; k < KC; ++k) A[idx*KC + k] = pr * c_lin[k];
    }
    __syncthreads();

    // slice geometry (fixed per thread)
    const int sk = tid / 144;
    const int q  = tid % 144;
    int base = 0, str = 0;
    if (tid < NSLICE) {
        if (sk == 0)      { base = q;                   str = 144; }
        else if (sk == 1) { base = (q/12)*144 + (q%12); str = 12;  }
        else              { base = q*12;                str = 1;   }
    }

    float logR = 0.f;   // accumulated log2 of per-step normalizers (identical in all threads)

    // ---------------- 64 sequential scan steps, all linear-space ----------------
    for (int t = 0; t < TLEN; ++t) {
        const int y = ys_s[t];

        // beta[s] = sum over chain label (linear == lse in log space), + partial for R
        float part = 0.f;
        for (int s = tid; s < SS; s += NTHREADS) {
            float b = A[s*KC+0] + A[s*KC+1] + A[s*KC+2];
            beta[s] = b;
            part += b;
        }
        #pragma unroll
        for (int off = 32; off > 0; off >>= 1) part += __shfl_xor(part, off);
        if ((tid & 63) == 0) wsum[tid >> 6] = part;
        __syncthreads();

        // every thread redundantly folds the 8 wave partials (no extra barrier)
        float R = wsum[0];
        #pragma unroll
        for (int w = 1; w < NWAVES; ++w) R += wsum[w];
        logR += __log2f(R);

        if (tid < NSLICE) {
            const float invR = __builtin_amdgcn_rcpf(R);
            float acc[S];
            #pragma unroll
            for (int j = 0; j < S; ++j) acc[j] = 0.f;
            #pragma unroll
            for (int i = 0; i < S; ++i) {
                const float bv = beta[base + i*str];
                const float4* tr = reinterpret_cast<const float4*>(&T[sk][i][0]);
                float4 t0 = tr[0], t1 = tr[1], t2 = tr[2];
                acc[0] += bv*t0.x; acc[1]  += bv*t0.y; acc[2]  += bv*t0.z; acc[3]  += bv*t0.w;
                acc[4] += bv*t1.x; acc[5]  += bv*t1.y; acc[6]  += bv*t1.z; acc[7]  += bv*t1.w;
                acc[8] += bv*t2.x; acc[9]  += bv*t2.y; acc[10] += bv*t2.z; acc[11] += bv*t2.w;
            }
            #pragma unroll
            for (int j = 0; j < S; ++j) {
                A[(base + j*str)*KC + sk] = acc[j] * EC[sk][j][y] * invR;
            }
        }
        __syncthreads();
    }

    // ---------------- final: out = ln2 * (log2(sum A) + sum_t log2(R_t)) ----------------
    float ssum = 0.f;
    for (int i = tid; i < SS*KC; i += NTHREADS) ssum += A[i];
    #pragma unroll
    for (int off = 32; off > 0; off >>= 1) ssum += __shfl_xor(ssum, off);
    const int wave = tid >> 6;
    if ((tid & 63) == 0) redm[wave] = ssum;
    __syncthreads();
    if (tid == 0) {
        float s = 0.f;
        #pragma unroll
        for (int w = 0; w < NWAVES; ++w) s += redm[w];
        out[0] = LN2F * (__log2f(s) + logR);
    }
}

extern "C" void kernel_launch(void* const* d_in, const int* in_sizes, int n_in,
                              void* d_out, int out_size, void* d_ws, size_t ws_size,
                              hipStream_t stream) {
    const int*   ys         = (const int*)  d_in[0];
    const float* transition = (const float*)d_in[1];
    const float* emission   = (const float*)d_in[2];
    const float* choice     = (const float*)d_in[3];
    const float* prior      = (const float*)d_in[4];
    float* out = (float*)d_out;

    hipLaunchKernelGGL(hmm_fwd_kernel, dim3(1), dim3(NTHREADS), 0, stream,
                       ys, transition, emission, choice, prior, out);
}

// Round 3
// 72.550 us; speedup vs baseline: 2.5225x; 1.4471x over previous
//
#include <hip/hip_runtime.h>
#include <math.h>

#define KC 3
#define S 12
#define SS 1728          // 12^3 composite states
#define AB 32
#define TLEN 64
#define NTHREADS 448
#define NWAVES 7
#define NSLICE 432
#define LN2F 0.69314718055994530942f

__global__ __launch_bounds__(NTHREADS, 2)
void hmm_fwd_kernel(const int* __restrict__ ys,
                    const float* __restrict__ transition,  // [3][12][12]
                    const float* __restrict__ emission,    // [3][12][32]
                    const float* __restrict__ choice,      // [3]
                    const float* __restrict__ prior,       // [3][12]
                    float* __restrict__ out)
{
    __shared__ __align__(16) float A[2][KC][SS];  // ping-pong scaled-linear alpha planes
    __shared__ __align__(16) float T_s[KC][S][S]; // transition softmax probs
    __shared__ float EC[KC][S][AB];               // C[k]*softmax(emission)
    __shared__ float p_lin[KC][S];
    __shared__ float c_lin[KC];
    __shared__ int   ys_s[TLEN];
    __shared__ float wsum[NWAVES];

    const int tid = threadIdx.x;

    // ---------------- setup: linear-space tables ----------------
    if (tid < TLEN) ys_s[tid] = ys[tid];

    if (tid == 0) {
        float m = fmaxf(fmaxf(choice[0], choice[1]), choice[2]);
        float e0 = __expf(choice[0]-m), e1 = __expf(choice[1]-m), e2 = __expf(choice[2]-m);
        float inv = 1.f / (e0+e1+e2);
        c_lin[0] = e0*inv; c_lin[1] = e1*inv; c_lin[2] = e2*inv;
    }
    if (tid >= 1 && tid < 1 + KC) {          // prior -> softmax probs
        int k = tid - 1;
        float m = -INFINITY;
        #pragma unroll
        for (int i = 0; i < S; ++i) m = fmaxf(m, prior[k*S + i]);
        float ev[S]; float s = 0.f;
        #pragma unroll
        for (int i = 0; i < S; ++i) { ev[i] = __expf(prior[k*S + i] - m); s += ev[i]; }
        float inv = 1.f / s;
        #pragma unroll
        for (int i = 0; i < S; ++i) p_lin[k][i] = ev[i] * inv;
    }
    if (tid >= 64 && tid < 64 + KC*S) {      // transition -> softmax probs
        int r = tid - 64;
        int k = r / S, i = r % S;
        const float* row = transition + (k*S + i)*S;
        float m = -INFINITY;
        #pragma unroll
        for (int j = 0; j < S; ++j) m = fmaxf(m, row[j]);
        float ev[S]; float s = 0.f;
        #pragma unroll
        for (int j = 0; j < S; ++j) { ev[j] = __expf(row[j] - m); s += ev[j]; }
        float inv = 1.f / s;
        #pragma unroll
        for (int j = 0; j < S; ++j) T_s[k][i][j] = ev[j] * inv;
    }
    if (tid >= 128 && tid < 128 + KC*S) {    // emission -> C[k]*softmax probs
        int r = tid - 128;
        int k = r / S, si = r % S;
        float cm = fmaxf(fmaxf(choice[0], choice[1]), choice[2]);
        float ce = __expf(choice[k]-cm) /
                   (__expf(choice[0]-cm) + __expf(choice[1]-cm) + __expf(choice[2]-cm));
        const float* row = emission + (k*S + si)*AB;
        float m = -INFINITY;
        #pragma unroll
        for (int a = 0; a < AB; ++a) m = fmaxf(m, row[a]);
        float ev[AB]; float s = 0.f;
        #pragma unroll
        for (int a = 0; a < AB; ++a) { ev[a] = __expf(row[a] - m); s += ev[a]; }
        float inv = ce / s;
        #pragma unroll
        for (int a = 0; a < AB; ++a) EC[k][si][a] = ev[a] * inv;
    }
    __syncthreads();

    // ---------------- per-thread slice geometry + T register preload + init ----------------
    const bool active = (tid < NSLICE);
    const int sk = tid / 144;                // chain (valid when active)
    const int q  = tid % 144;
    const int ka = (sk == 0) ? 1 : 0;        // the two "other" planes
    const int kb = (sk == 2) ? 1 : 2;

    int base = 0, str = 0;
    float2 T2[S][6];                         // this chain's T, fully in registers
    float  own[S];                           // values this thread wrote last step
    int    off[S];                           // LDS word offsets of this thread's positions

    if (active) {
        if (sk == 0)      { base = q;                   str = 144; }
        else if (sk == 1) { base = (q/12)*144 + (q%12); str = 12;  }
        else              { base = q*12;                str = 1;   }
        #pragma unroll
        for (int i = 0; i < S; ++i) off[i] = base + i*str;

        #pragma unroll
        for (int i = 0; i < S; ++i) {
            const float2* tr = reinterpret_cast<const float2*>(&T_s[sk][i][0]);
            #pragma unroll
            for (int m = 0; m < 6; ++m) T2[i][m] = tr[m];
        }

        // A0[(s,k)] = prior-product * C[k]  (each entry owned by exactly one slice thread)
        const float pq = p_lin[ka == 1 ? 1 : 0][q/12] * 0.f + // (dummy to keep structure clear)
                         p_lin[(sk==0)?1:0][q/12] * p_lin[(sk==2)?1:2][q%12];
        const float ck = c_lin[sk];
        #pragma unroll
        for (int i = 0; i < S; ++i) {
            float v = p_lin[sk][i] * pq * ck;
            own[i] = v;
            A[0][sk][off[i]] = v;
        }
    }
    __syncthreads();

    // ---------------- 64 steps, 1 barrier each ----------------
    float logR = 0.f;
    float invR = 1.f;
    int cur = 0;

    for (int t = 0; t < TLEN; ++t) {
        const int y = ys_s[t];

        if (active) {
            float ecol[S];
            #pragma unroll
            for (int j = 0; j < S; ++j) ecol[j] = EC[sk][j][y];   // broadcast reads

            float beta[S];
            if (sk == 2) {                                        // contiguous: float4 path
                const float4* pa = reinterpret_cast<const float4*>(&A[cur][0][base]);
                const float4* pb = reinterpret_cast<const float4*>(&A[cur][1][base]);
                #pragma unroll
                for (int m = 0; m < 3; ++m) {
                    float4 x = pa[m], z = pb[m];
                    beta[4*m+0] = own[4*m+0] + x.x + z.x;
                    beta[4*m+1] = own[4*m+1] + x.y + z.y;
                    beta[4*m+2] = own[4*m+2] + x.z + z.z;
                    beta[4*m+3] = own[4*m+3] + x.w + z.w;
                }
            } else {                                              // strided scalar path
                #pragma unroll
                for (int i = 0; i < S; ++i)
                    beta[i] = own[i] + A[cur][ka][off[i]] + A[cur][kb][off[i]];
            }

            float2 acc2[6];
            #pragma unroll
            for (int m = 0; m < 6; ++m) { acc2[m].x = 0.f; acc2[m].y = 0.f; }
            #pragma unroll
            for (int i = 0; i < S; ++i) {
                const float bv = beta[i];
                #pragma unroll
                for (int m = 0; m < 6; ++m) {
                    acc2[m].x += bv * T2[i][m].x;
                    acc2[m].y += bv * T2[i][m].y;
                }
            }

            #pragma unroll
            for (int j = 0; j < S; ++j) {
                float a = (j & 1) ? acc2[j>>1].y : acc2[j>>1].x;
                own[j] = a * ecol[j] * invR;
            }

            if (sk == 2) {
                float4* pw = reinterpret_cast<float4*>(&A[cur^1][2][base]);
                pw[0] = make_float4(own[0], own[1], own[2],  own[3]);
                pw[1] = make_float4(own[4], own[5], own[6],  own[7]);
                pw[2] = make_float4(own[8], own[9], own[10], own[11]);
            } else {
                #pragma unroll
                for (int j = 0; j < S; ++j) A[cur^1][sk][off[j]] = own[j];
            }
        }

        // every 8th step: reduce total mass from the just-written registers
        if ((t & 7) == 7) {
            float part = 0.f;
            if (active) {
                #pragma unroll
                for (int j = 0; j < S; ++j) part += own[j];
            }
            #pragma unroll
            for (int o = 32; o > 0; o >>= 1) part += __shfl_xor(part, o);
            if ((tid & 63) == 0) wsum[tid >> 6] = part;
        }
        __syncthreads();

        if ((t & 7) == 7 && t < TLEN-1) {
            float R = wsum[0];
            #pragma unroll
            for (int w = 1; w < NWAVES; ++w) R += wsum[w];
            invR = __builtin_amdgcn_rcpf(R);
            logR += __log2f(R);
        } else {
            invR = 1.f;
        }
        cur ^= 1;
    }

    // final: sum of final A == R at t=63 (unapplied), already in wsum
    if (tid == 0) {
        float R = wsum[0];
        #pragma unroll
        for (int w = 1; w < NWAVES; ++w) R += wsum[w];
        out[0] = LN2F * (__log2f(R) + logR);
    }
}

extern "C" void kernel_launch(void* const* d_in, const int* in_sizes, int n_in,
                              void* d_out, int out_size, void* d_ws, size_t ws_size,
                              hipStream_t stream) {
    const int*   ys         = (const int*)  d_in[0];
    const float* transition = (const float*)d_in[1];
    const float* emission   = (const float*)d_in[2];
    const float* choice     = (const float*)d_in[3];
    const float* prior      = (const float*)d_in[4];
    float* out = (float*)d_out;

    hipLaunchKernelGGL(hmm_fwd_kernel, dim3(1), dim3(NTHREADS), 0, stream,
                       ys, transition, emission, choice, prior, out);
}

// Round 4
// 65.465 us; speedup vs baseline: 2.7955x; 1.1082x over previous
//
#include <hip/hip_runtime.h>
#include <math.h>

#define KC 3
#define S 12
#define SS 1728
#define AB 32
#define TLEN 64
#define NTHREADS 448
#define NWAVES 7
#define NSLICE 432
#define LN2F 0.69314718055994530942f

// Swizzled word offset for 64B-row arrays (144 rows x 12 floats, padded to 16).
// n = natural state index in [0,1728). Bijective into [0,2304) words.
__device__ __forceinline__ int swz_word(int n) {
    int r   = n / 12;
    int pos = n % 12;
    int v = (((r & 1) << 2) | (pos >> 2)) ^ ((r >> 1) & 7);
    return ((r >> 1) << 5) + (v << 2) + (pos & 3);
}

__global__ __launch_bounds__(NTHREADS, 2)
void hmm_fwd_kernel(const int* __restrict__ ys,
                    const float* __restrict__ transition,  // [3][12][12]
                    const float* __restrict__ emission,    // [3][12][32]
                    const float* __restrict__ choice,      // [3]
                    const float* __restrict__ prior,       // [3][12]
                    float* __restrict__ out)
{
    // A0 natural [0,1728), A1 natural [1728,3456), A2 swizzled [3456,5760)
    __shared__ __align__(16) float ABUF[5760];
    __shared__ __align__(16) float BETA[2304];      // swizzled
    __shared__ __align__(16) float ECt[KC*AB*S];    // [k][y][j]
    __shared__ float T_s[KC][S][S];
    __shared__ float p_lin[KC][S];
    __shared__ float c_lin[KC];
    __shared__ int   ys_s[TLEN];
    __shared__ float wsum[NWAVES];

    const int tid = threadIdx.x;

    // ---------------- setup: linear-space tables ----------------
    if (tid < TLEN) ys_s[tid] = ys[tid];

    if (tid == 0) {
        float m = fmaxf(fmaxf(choice[0], choice[1]), choice[2]);
        float e0 = __expf(choice[0]-m), e1 = __expf(choice[1]-m), e2 = __expf(choice[2]-m);
        float inv = 1.f / (e0+e1+e2);
        c_lin[0] = e0*inv; c_lin[1] = e1*inv; c_lin[2] = e2*inv;
    }
    if (tid >= 1 && tid < 1 + KC) {
        int k = tid - 1;
        float m = -INFINITY;
        #pragma unroll
        for (int i = 0; i < S; ++i) m = fmaxf(m, prior[k*S + i]);
        float ev[S]; float s = 0.f;
        #pragma unroll
        for (int i = 0; i < S; ++i) { ev[i] = __expf(prior[k*S + i] - m); s += ev[i]; }
        float inv = 1.f / s;
        #pragma unroll
        for (int i = 0; i < S; ++i) p_lin[k][i] = ev[i] * inv;
    }
    if (tid >= 64 && tid < 64 + KC*S) {
        int r = tid - 64;
        int k = r / S, i = r % S;
        const float* row = transition + (k*S + i)*S;
        float m = -INFINITY;
        #pragma unroll
        for (int j = 0; j < S; ++j) m = fmaxf(m, row[j]);
        float ev[S]; float s = 0.f;
        #pragma unroll
        for (int j = 0; j < S; ++j) { ev[j] = __expf(row[j] - m); s += ev[j]; }
        float inv = 1.f / s;
        #pragma unroll
        for (int j = 0; j < S; ++j) T_s[k][i][j] = ev[j] * inv;
    }
    if (tid >= 128 && tid < 128 + KC*S) {    // emission rows -> ECt[k][y][j] = C[k]*softmax
        int r = tid - 128;
        int k = r / S, sj = r % S;
        float cm = fmaxf(fmaxf(choice[0], choice[1]), choice[2]);
        float ce = __expf(choice[k]-cm) /
                   (__expf(choice[0]-cm) + __expf(choice[1]-cm) + __expf(choice[2]-cm));
        const float* row = emission + (k*S + sj)*AB;
        float m = -INFINITY;
        #pragma unroll
        for (int a = 0; a < AB; ++a) m = fmaxf(m, row[a]);
        float ev[AB]; float s = 0.f;
        #pragma unroll
        for (int a = 0; a < AB; ++a) { ev[a] = __expf(row[a] - m); s += ev[a]; }
        float inv = ce / s;
        #pragma unroll
        for (int a = 0; a < AB; ++a) ECt[(k*AB + a)*S + sj] = ev[a] * inv;
    }
    __syncthreads();

    // ---------------- per-thread statics: addresses, T registers, init ----------------
    const bool active = tid < NSLICE;
    const int sk = tid / 144;
    const int q  = tid % 144;

    int rd[S], wr[S];
    float4 T4[S][3];

    if (active) {
        int n[S];
        if (sk == 0) {
            #pragma unroll
            for (int j = 0; j < S; ++j) n[j] = j*144 + q;
        } else if (sk == 1) {
            int b = (q/12)*144 + (q%12);
            #pragma unroll
            for (int j = 0; j < S; ++j) n[j] = b + j*12;
        } else {
            #pragma unroll
            for (int j = 0; j < S; ++j) n[j] = q*12 + j;
        }
        #pragma unroll
        for (int j = 0; j < S; ++j) rd[j] = swz_word(n[j]);
        #pragma unroll
        for (int j = 0; j < S; ++j)
            wr[j] = (sk == 0) ? n[j] : (sk == 1 ? 1728 + n[j] : 3456 + swz_word(n[j]));

        #pragma unroll
        for (int i = 0; i < S; ++i) {
            #pragma unroll
            for (int c = 0; c < 3; ++c) {
                T4[i][c] = *reinterpret_cast<const float4*>(&T_s[sk][i][4*c]);
                asm volatile("" : "+v"(T4[i][c].x), "+v"(T4[i][c].y),
                                  "+v"(T4[i][c].z), "+v"(T4[i][c].w));
            }
        }

        // init A0[s,k] = prod of prior probs * C[k]
        float pq = (sk == 0) ? p_lin[1][q/12] * p_lin[2][q%12]
                 : (sk == 1) ? p_lin[0][q/12] * p_lin[2][q%12]
                 :             p_lin[0][q/12] * p_lin[1][q%12];
        float ck = c_lin[sk];
        #pragma unroll
        for (int j = 0; j < S; ++j) ABUF[wr[j]] = p_lin[sk][j] * pq * ck;
    }
    // phase-1 static swizzled chunk offset (thread p handles states 4p..4p+3)
    const int p13 = tid / 3, pm3 = tid % 3;
    const int swzw = ((p13 >> 1) << 5) + ((((((p13 & 1) << 2) | pm3)) ^ ((p13 >> 1) & 7)) << 2);
    __syncthreads();

    // ---------------- 64 steps, 2 barriers each ----------------
    float logR = 0.f, invR = 1.f;

    for (int t = 0; t < TLEN; ++t) {
        const int y = ys_s[t];
        float4 b4, e0, e1, e2;

        if (active) {
            // phase 1: beta for 4 contiguous states (wide, conflict-free)
            float4 a0 = *reinterpret_cast<const float4*>(&ABUF[4*tid]);
            float4 a1 = *reinterpret_cast<const float4*>(&ABUF[1728 + 4*tid]);
            float4 a2 = *reinterpret_cast<const float4*>(&ABUF[3456 + swzw]);
            b4.x = a0.x + a1.x + a2.x;
            b4.y = a0.y + a1.y + a2.y;
            b4.z = a0.z + a1.z + a2.z;
            b4.w = a0.w + a1.w + a2.w;
            *reinterpret_cast<float4*>(&BETA[swzw]) = b4;
            // ecol prefetch for this step (read-only table, no hazard)
            const float* eb = &ECt[(sk*AB + y)*S];
            e0 = *reinterpret_cast<const float4*>(&eb[0]);
            e1 = *reinterpret_cast<const float4*>(&eb[4]);
            e2 = *reinterpret_cast<const float4*>(&eb[8]);
        }
        __syncthreads();   // barrier A: BETA ready

        float4 o0, o1, o2;
        if (active) {
            float bv[S];
            #pragma unroll
            for (int i = 0; i < S; ++i) bv[i] = BETA[rd[i]];

            float4 acc0 = {0,0,0,0}, acc1 = {0,0,0,0}, acc2 = {0,0,0,0};
            #pragma unroll
            for (int i = 0; i < S; ++i) {
                const float b = bv[i];
                acc0.x += b*T4[i][0].x; acc0.y += b*T4[i][0].y;
                acc0.z += b*T4[i][0].z; acc0.w += b*T4[i][0].w;
                acc1.x += b*T4[i][1].x; acc1.y += b*T4[i][1].y;
                acc1.z += b*T4[i][1].z; acc1.w += b*T4[i][1].w;
                acc2.x += b*T4[i][2].x; acc2.y += b*T4[i][2].y;
                acc2.z += b*T4[i][2].z; acc2.w += b*T4[i][2].w;
            }
            o0.x = acc0.x*e0.x*invR; o0.y = acc0.y*e0.y*invR;
            o0.z = acc0.z*e0.z*invR; o0.w = acc0.w*e0.w*invR;
            o1.x = acc1.x*e1.x*invR; o1.y = acc1.y*e1.y*invR;
            o1.z = acc1.z*e1.z*invR; o1.w = acc1.w*e1.w*invR;
            o2.x = acc2.x*e2.x*invR; o2.y = acc2.y*e2.y*invR;
            o2.z = acc2.z*e2.z*invR; o2.w = acc2.w*e2.w*invR;

            ABUF[wr[0]]  = o0.x; ABUF[wr[1]]  = o0.y; ABUF[wr[2]]  = o0.z; ABUF[wr[3]]  = o0.w;
            ABUF[wr[4]]  = o1.x; ABUF[wr[5]]  = o1.y; ABUF[wr[6]]  = o1.z; ABUF[wr[7]]  = o1.w;
            ABUF[wr[8]]  = o2.x; ABUF[wr[9]]  = o2.y; ABUF[wr[10]] = o2.z; ABUF[wr[11]] = o2.w;
        }

        if ((t & 7) == 7) {
            float part = 0.f;
            if (active) {
                part = (o0.x+o0.y+o0.z+o0.w) + (o1.x+o1.y+o1.z+o1.w) + (o2.x+o2.y+o2.z+o2.w);
            }
            #pragma unroll
            for (int o = 32; o > 0; o >>= 1) part += __shfl_xor(part, o);
            if ((tid & 63) == 0) wsum[tid >> 6] = part;
        }
        __syncthreads();   // barrier B: planes ready; wsum ready on reduce steps

        if ((t & 7) == 7 && t < TLEN-1) {
            float R = wsum[0];
            #pragma unroll
            for (int w = 1; w < NWAVES; ++w) R += wsum[w];
            invR = __builtin_amdgcn_rcpf(R);
            logR += __log2f(R);
        } else {
            invR = 1.f;
        }
    }

    // final: sum of final outputs (t=63 partials already in wsum)
    if (tid == 0) {
        float R = wsum[0];
        #pragma unroll
        for (int w = 1; w < NWAVES; ++w) R += wsum[w];
        out[0] = LN2F * (__log2f(R) + logR);
    }
}

extern "C" void kernel_launch(void* const* d_in, const int* in_sizes, int n_in,
                              void* d_out, int out_size, void* d_ws, size_t ws_size,
                              hipStream_t stream) {
    const int*   ys         = (const int*)  d_in[0];
    const float* transition = (const float*)d_in[1];
    const float* emission   = (const float*)d_in[2];
    const float* choice     = (const float*)d_in[3];
    const float* prior      = (const float*)d_in[4];
    float* out = (float*)d_out;

    hipLaunchKernelGGL(hmm_fwd_kernel, dim3(1), dim3(NTHREADS), 0, stream,
                       ys, transition, emission, choice, prior, out);
}